// Round 3
// baseline (478.019 us; speedup 1.0000x reference)
//
#include <hip/hip_runtime.h>

// GraphAugmentation fused kernel, MI355X — R3.
//
// Algebra (unchanged):
//  * softmax over 8 identical affinities == uniform 1/8 -> Q/K/attn dead.
//  * agg = conv1x1(mean_of_8_rolls(x), mw, mb)  (roll commutes with 1x1 conv).
//  * out = agg * sigmoid(g2 @ relu(g1 @ [x; agg]))
//
// R3 vs R2 (R2 was L2-latency-bound at 21% occupancy, VGPR=88):
//  * keep the XCD swizzle (proven: FETCH 207->40 MB)
//  * P=1 pixel/thread, 4096 x 256 -> 2x waves, oversubscribed CUs
//  * register-lean fusion: mw-matmul fused into gather loop (xavg dies
//    per-channel), g2 accumulation fused into g1 j-loop (hd dies per-j).
//    Peak live ~60 floats -> force 8 waves/SIMD via __launch_bounds__(256,8).

#define HW 262144   // 512*512
#define WD 512

__global__ __launch_bounds__(256, 8) void ga_fused(
    const float* __restrict__ x,
    const float* __restrict__ mw,  const float* __restrict__ mb,
    const float* __restrict__ g1w, const float* __restrict__ g1b,
    const float* __restrict__ g2w, const float* __restrict__ g2b,
    float* __restrict__ out)
{
  // Fixed offsets (dy,dx) from the reference OFFSETS list.
  constexpr int DY[8] = {-4, -4, -4, -3, -2, 2, 3, 4};
  constexpr int DX[8] = {-4, -1,  2,  4, -3, 3, -2, 4};

  // ---- XCD-aware bijective swizzle: nwg=4096 (%8==0), chunk=512 ----
  const int bid = blockIdx.x;
  const int sw  = ((bid & 7) << 9) + (bid >> 3);  // XCD k owns sw in [k*512,(k+1)*512)
  const int b    = sw >> 10;         // batch (1024 wgs per image)
  const int r    = (sw >> 1) & 511;  // row
  const int half = sw & 1;           // which half-row
  const int w    = (half << 8) + threadIdx.x;   // this thread's pixel column

  const float* xb = x + b * 16 * HW;
  const int rowbase = r * WD;

  // ---- 8 gather element-offsets (32-bit), live through the channel loop ----
  unsigned off[8];
#pragma unroll
  for (int i = 0; i < 8; ++i)
    off[i] = ((r - DY[i]) & 511) * WD + ((w - DX[i]) & 511);

  // ---- phase 1+2: per channel, gather-average; fuse mw matmul so xavg dies.
  //      ag[cc] = mb[cc] + sum_c mw[cc*16+c] * xavg_c ; xc[c] = center x.
  float xc[16], ag[16];
#pragma unroll
  for (int cc = 0; cc < 16; ++cc) ag[cc] = mb[cc];

#pragma unroll
  for (int c = 0; c < 16; ++c) {
    const float* xp = xb + c * HW;
    xc[c] = xp[rowbase + w];
    float s = 0.f;
#pragma unroll
    for (int i = 0; i < 8; ++i) s += xp[off[i]];
    const float xa = s * 0.125f;
#pragma unroll
    for (int cc = 0; cc < 16; ++cc)
      ag[cc] = fmaf(mw[cc * 16 + c], xa, ag[cc]);   // mw: wave-uniform scalar load
  }

  // ---- phase 3: fused g1 -> relu -> g2 accumulation (hd_j dies per-j) ----
  float sg[16];
#pragma unroll
  for (int c = 0; c < 16; ++c) sg[c] = g2b[c];

#pragma unroll
  for (int j = 0; j < 32; ++j) {
    float s = g1b[j];
#pragma unroll
    for (int k = 0; k < 16; ++k) {
      s = fmaf(g1w[j * 32 + k],      xc[k], s);
      s = fmaf(g1w[j * 32 + 16 + k], ag[k], s);
    }
    const float hd = fmaxf(s, 0.f);
#pragma unroll
    for (int c = 0; c < 16; ++c)
      sg[c] = fmaf(g2w[c * 32 + j], hd, sg[c]);     // g2w: wave-uniform scalar load
  }

  // ---- epilogue: out = ag * sigmoid(sg) ----
  float* ob = out + b * 16 * HW + rowbase + w;
#pragma unroll
  for (int c = 0; c < 16; ++c) {
    const float gt = 1.0f / (1.0f + __expf(-sg[c]));
    ob[c * HW] = ag[c] * gt;
  }
}

extern "C" void kernel_launch(void* const* d_in, const int* in_sizes, int n_in,
                              void* d_out, int out_size, void* d_ws, size_t ws_size,
                              hipStream_t stream) {
  // setup_inputs() order:
  // 0:x 1:qw 2:qb 3:kw 4:kb 5:mw 6:mb 7:scaling 8:g1w 9:g1b 10:g2w 11:g2b
  const float* x   = (const float*)d_in[0];
  const float* mw  = (const float*)d_in[5];
  const float* mb  = (const float*)d_in[6];
  const float* g1w = (const float*)d_in[8];
  const float* g1b = (const float*)d_in[9];
  const float* g2w = (const float*)d_in[10];
  const float* g2b = (const float*)d_in[11];
  float* out = (float*)d_out;

  // 4096 wgs x 256 threads; each wg = half an image row, 1 px/thread.
  ga_fused<<<4096, 256, 0, stream>>>(x, mw, mb, g1w, g1b, g2w, g2b, out);
}

// Round 4
// 283.520 us; speedup vs baseline: 1.6860x; 1.6860x over previous
//
#include <hip/hip_runtime.h>

// GraphAugmentation fused kernel, MI355X — R4.
//
// Algebra (unchanged):
//  * softmax over 8 identical affinities == uniform 1/8 -> Q/K/attn dead.
//  * agg = conv1x1(mean_of_8_rolls(x), mw, mb)  (roll commutes with 1x1 conv).
//  * out = agg * sigmoid(g2 @ relu(g1 @ [x; agg]))
//
// R4 vs R1/R2/R3:
//  * R1's proven block shape: 1 block = 1 image row, 256 thr, px (t, t+256).
//  * XCD bijective swizzle (R2-proven: FETCH 207->40 MB), chunk = 256.
//  * ALL per-pixel arithmetic on float2 ext-vectors via elementwise fma ->
//    v_pk_fma_f32 (VOP3P packed fp32) halves VALU cycles for the ~1800
//    FMAs/px that dominate the compute floor.
//  * register-lean fusion (mw into gather loop, g2 into g1 j-loop) but NO
//    min-waves forcing (R3's VGPR=28 spill disaster).
//  * sigmoid via v_rcp_f32 intrinsic instead of exact fp32 divide.

#define HW 262144   // 512*512
#define WD 512

typedef float f32x2 __attribute__((ext_vector_type(2)));

__global__ __launch_bounds__(256) void ga_fused(
    const float* __restrict__ x,
    const float* __restrict__ mw,  const float* __restrict__ mb,
    const float* __restrict__ g1w, const float* __restrict__ g1b,
    const float* __restrict__ g2w, const float* __restrict__ g2b,
    float* __restrict__ out)
{
  // Fixed offsets (dy,dx) from the reference OFFSETS list.
  constexpr int DY[8] = {-4, -4, -4, -3, -2, 2, 3, 4};
  constexpr int DX[8] = {-4, -1,  2,  4, -3, 3, -2, 4};

  // ---- XCD-aware bijective swizzle: nwg=2048, 8 XCDs, chunk=256 ----
  const int bid = blockIdx.x;
  const int sw  = ((bid & 7) << 8) + (bid >> 3); // XCD k owns sw in [k*256,(k+1)*256)
  const int b   = sw >> 9;          // batch (512 rows per image)
  const int r   = sw & 511;         // image row
  const int t   = threadIdx.x;
  const int w0  = t;                // pixel 0
  const int w1  = t + 256;          // pixel 1

  const float* xb = x + b * 16 * HW;
  const int rowbase = r * WD;

  // ---- gather element-offsets for both pixels (live through phase 1) ----
  unsigned off0[8], off1[8];
#pragma unroll
  for (int i = 0; i < 8; ++i) {
    const unsigned ro = ((r - DY[i]) & 511) * WD;
    off0[i] = ro + ((w0 - DX[i]) & 511);
    off1[i] = ro + ((w1 - DX[i]) & 511);
  }

  // ---- phase 1+2: gather-average per channel, mw matmul fused (xavg dies).
  f32x2 xc[16], ag[16];
#pragma unroll
  for (int cc = 0; cc < 16; ++cc) {
    const float bv = mb[cc];
    ag[cc] = (f32x2){bv, bv};
  }

#pragma unroll
  for (int c = 0; c < 16; ++c) {
    const float* xp = xb + c * HW;
    xc[c] = (f32x2){xp[rowbase + w0], xp[rowbase + w1]};
    f32x2 s = (f32x2){0.f, 0.f};
#pragma unroll
    for (int i = 0; i < 8; ++i)
      s += (f32x2){xp[off0[i]], xp[off1[i]]};      // v_pk_add_f32
    const f32x2 xa = s * 0.125f;
#pragma unroll
    for (int cc = 0; cc < 16; ++cc) {
      const float wv = mw[cc * 16 + c];            // wave-uniform scalar load
      ag[cc] = __builtin_elementwise_fma((f32x2){wv, wv}, xa, ag[cc]); // v_pk_fma_f32
    }
  }

  // ---- phase 3: fused g1 -> relu -> g2 accumulation (hd dies per-j) ----
  f32x2 sg[16];
#pragma unroll
  for (int c = 0; c < 16; ++c) {
    const float bv = g2b[c];
    sg[c] = (f32x2){bv, bv};
  }

#pragma unroll
  for (int j = 0; j < 32; ++j) {
    const float bj = g1b[j];
    f32x2 s = (f32x2){bj, bj};
#pragma unroll
    for (int k = 0; k < 16; ++k) {
      const float wx = g1w[j * 32 + k];
      const float wa = g1w[j * 32 + 16 + k];
      s = __builtin_elementwise_fma((f32x2){wx, wx}, xc[k], s);
      s = __builtin_elementwise_fma((f32x2){wa, wa}, ag[k], s);
    }
    const f32x2 hd = __builtin_elementwise_max(s, (f32x2){0.f, 0.f});
#pragma unroll
    for (int c = 0; c < 16; ++c) {
      const float wv = g2w[c * 32 + j];
      sg[c] = __builtin_elementwise_fma((f32x2){wv, wv}, hd, sg[c]);
    }
  }

  // ---- epilogue: out = ag * sigmoid(sg) ----
  float* ob = out + b * 16 * HW + rowbase;
#pragma unroll
  for (int c = 0; c < 16; ++c) {
    const float g0 = __builtin_amdgcn_rcpf(1.0f + __expf(-sg[c].x));
    const float g1 = __builtin_amdgcn_rcpf(1.0f + __expf(-sg[c].y));
    ob[c * HW + w0] = ag[c].x * g0;
    ob[c * HW + w1] = ag[c].y * g1;
  }
}

extern "C" void kernel_launch(void* const* d_in, const int* in_sizes, int n_in,
                              void* d_out, int out_size, void* d_ws, size_t ws_size,
                              hipStream_t stream) {
  // setup_inputs() order:
  // 0:x 1:qw 2:qb 3:kw 4:kb 5:mw 6:mb 7:scaling 8:g1w 9:g1b 10:g2w 11:g2b
  const float* x   = (const float*)d_in[0];
  const float* mw  = (const float*)d_in[5];
  const float* mb  = (const float*)d_in[6];
  const float* g1w = (const float*)d_in[8];
  const float* g1b = (const float*)d_in[9];
  const float* g2w = (const float*)d_in[10];
  const float* g2b = (const float*)d_in[11];
  float* out = (float*)d_out;

  // 2048 wgs x 256 threads; each wg = one image row, 2 px/thread.
  ga_fused<<<2048, 256, 0, stream>>>(x, mw, mb, g1w, g1b, g2w, g2b, out);
}

// Round 5
// 175.287 us; speedup vs baseline: 2.7271x; 1.6175x over previous
//
#include <hip/hip_runtime.h>

// GraphAugmentation fused kernel, MI355X — R5: MFMA fp16-split version.
//
// Algebra:
//  * softmax over 8 identical affinities == 1/8 -> Q/K/attn dead.
//  * u = [xc ; xavg] (K=32), xavg = mean of 8 rolls of x.
//  * agg    = Abar @ u + mb,   Abar = [0 | mw]                (16x32)
//  * hidden = relu(W1' @ u + b1'), W1' = [g1w_x | g1w_a@mw],
//             b1' = g1b + g1w_a@mb                            (32x32)
//  * gate   = sigmoid(g2w @ hidden + g2b)                     (16x32)
//  * out    = agg * gate
// All matmuls on the matrix pipe via mfma_f32_16x16x32_f16, with each
// operand split fp16 hi+lo and 3 MFMA passes (AloBhi+AhiBlo+AhiBhi) ->
// ~2^-23 rel error, preserving the fp32-level absmax.
//
// Structure: block = 256 thr = 4 independent waves; wave = 64 px of one row.
// Wave-private LDS staging (no __syncthreads, lgkmcnt fences only), XOR
// chunk-swizzle (chunk ^= px&3) for bank-conflict-free b128 reads.
// Weight fragments + biases precomputed per launch by ga_prep into d_ws.

#define HW 262144   // 512*512

typedef _Float16 half8 __attribute__((ext_vector_type(8)));
typedef _Float16 half2 __attribute__((ext_vector_type(2)));
typedef float f32x4 __attribute__((ext_vector_type(4)));

#define LDS_FENCE() do { asm volatile("s_waitcnt lgkmcnt(0)" ::: "memory"); \
                         __builtin_amdgcn_sched_barrier(0); } while (0)

__device__ __forceinline__ void store_frag(_Float16* wf, int tile, int l,
                                           const float* v) {
  half8 hi, lo;
#pragma unroll
  for (int e = 0; e < 8; ++e) {
    _Float16 h = (_Float16)v[e];
    hi[e] = h;
    lo[e] = (_Float16)(v[e] - (float)h);
  }
  *(half8*)(wf + (tile * 64 + l) * 16 + 0) = hi;
  *(half8*)(wf + (tile * 64 + l) * 16 + 8) = lo;
}

// ---- prep: build per-lane A-fragments (fp16 hi/lo) + folded biases ----
__global__ void ga_prep(const float* __restrict__ mw, const float* __restrict__ mb,
                        const float* __restrict__ g1w, const float* __restrict__ g1b,
                        const float* __restrict__ g2w, const float* __restrict__ g2b,
                        _Float16* __restrict__ wf, float* __restrict__ wb) {
  const int l = threadIdx.x & 63;
  const int q = l >> 4, m = l & 15;
  float v[8];

  // tile 0: Abar = [0 | mw], row m
#pragma unroll
  for (int e = 0; e < 8; ++e) {
    const int k = q * 8 + e;
    v[e] = (k < 16) ? 0.f : mw[m * 16 + (k - 16)];
  }
  store_frag(wf, 0, l, v);

  // tiles 1,2: W1' rows m and 16+m
#pragma unroll
  for (int t = 0; t < 2; ++t) {
    const int j = t * 16 + m;
#pragma unroll
    for (int e = 0; e < 8; ++e) {
      const int k = q * 8 + e;
      if (k < 16) {
        v[e] = g1w[j * 32 + k];
      } else {
        float s = 0.f;
#pragma unroll
        for (int tt = 0; tt < 16; ++tt)
          s += g1w[j * 32 + 16 + tt] * mw[tt * 16 + (k - 16)];
        v[e] = s;
      }
    }
    store_frag(wf, 1 + t, l, v);
  }

  // tile 3: g2w row m
#pragma unroll
  for (int e = 0; e < 8; ++e) v[e] = g2w[m * 32 + q * 8 + e];
  store_frag(wf, 3, l, v);

  // biases: [0..3]=mb[4q+r], [4..7]=b1'[4q+r], [8..11]=b1'[16+4q+r], [12..15]=g2b[4q+r]
#pragma unroll
  for (int rg = 0; rg < 4; ++rg) wb[l * 16 + rg] = mb[4 * q + rg];
#pragma unroll
  for (int t = 0; t < 2; ++t) {
#pragma unroll
    for (int rg = 0; rg < 4; ++rg) {
      const int j = t * 16 + 4 * q + rg;
      float s = g1b[j];
#pragma unroll
      for (int tt = 0; tt < 16; ++tt) s += g1w[j * 32 + 16 + tt] * mb[tt];
      wb[l * 16 + 4 + t * 4 + rg] = s;
    }
  }
#pragma unroll
  for (int rg = 0; rg < 4; ++rg) wb[l * 16 + 12 + rg] = g2b[4 * q + rg];
}

// ---- main fused kernel ----
__global__ __launch_bounds__(256) void ga_main(
    const float* __restrict__ x, const _Float16* __restrict__ wf,
    const float* __restrict__ wb, float* __restrict__ out) {
  constexpr int DY[8] = {-4, -4, -4, -3, -2, 2, 3, 4};
  constexpr int DX[8] = {-4, -1,  2,  4, -3, 3, -2, 4};

  __shared__ _Float16 u_hi[4 * 64 * 32];   // 16 KB
  __shared__ _Float16 u_lo[4 * 64 * 32];   // 16 KB
  __shared__ _Float16 h_hi[4 * 16 * 32];   //  4 KB
  __shared__ _Float16 h_lo[4 * 16 * 32];   //  4 KB

  const int tid = threadIdx.x;
  const int wv = tid >> 6, lane = tid & 63;
  const int q = lane >> 4, m = lane & 15;

  // XCD-aware bijective swizzle: 4096 wgs, chunk 512
  const int swz = ((blockIdx.x & 7) << 9) | (blockIdx.x >> 3);
  const int b = swz >> 10;
  const int rem = swz & 1023;
  const int row = rem >> 1;
  const int colbase = ((rem & 1) << 8) + wv * 64;
  const int cw = colbase + lane;

  const float* xb = x + b * 16 * HW;

  unsigned off[8];
#pragma unroll
  for (int i = 0; i < 8; ++i)
    off[i] = ((row - DY[i]) & 511) * 512 + ((cw - DX[i]) & 511);
  const unsigned ctr = row * 512 + cw;

  // gathers: xc (center), xa (mean of 8 rolls)
  float xc[16], xa[16];
#pragma unroll
  for (int c = 0; c < 16; ++c) {
    const float* xp = xb + c * HW;
    xc[c] = xp[ctr];
    float s = 0.f;
#pragma unroll
    for (int i = 0; i < 8; ++i) s += xp[off[i]];
    xa[c] = s * 0.125f;
  }

  // per-lane A-fragments + biases (prep kernel output; L2-hot broadcast)
  const half8 aAg_h = *(const half8*)(wf + (0 * 64 + lane) * 16 + 0);
  const half8 aAg_l = *(const half8*)(wf + (0 * 64 + lane) * 16 + 8);
  const half8 aH0_h = *(const half8*)(wf + (1 * 64 + lane) * 16 + 0);
  const half8 aH0_l = *(const half8*)(wf + (1 * 64 + lane) * 16 + 8);
  const half8 aH1_h = *(const half8*)(wf + (2 * 64 + lane) * 16 + 0);
  const half8 aH1_l = *(const half8*)(wf + (2 * 64 + lane) * 16 + 8);
  const half8 aG2_h = *(const half8*)(wf + (3 * 64 + lane) * 16 + 0);
  const half8 aG2_l = *(const half8*)(wf + (3 * 64 + lane) * 16 + 8);
  const f32x4 bias0 = *(const f32x4*)(wb + lane * 16 + 0);
  const f32x4 bias1 = *(const f32x4*)(wb + lane * 16 + 4);
  const f32x4 bias2 = *(const f32x4*)(wb + lane * 16 + 8);
  const f32x4 bias3 = *(const f32x4*)(wb + lane * 16 + 12);

  // split u=[xc;xa] into fp16 hi/lo and write to wave-private LDS
  _Float16* uh = u_hi + (wv * 64 + lane) * 32;
  _Float16* ul = u_lo + (wv * 64 + lane) * 32;
#pragma unroll
  for (int j = 0; j < 4; ++j) {
    half8 vh, vl;
#pragma unroll
    for (int e = 0; e < 8; ++e) {
      const int k = j * 8 + e;
      const float val = (k < 16) ? xc[k] : xa[k - 16];
      const _Float16 h = (_Float16)val;
      vh[e] = h;
      vl[e] = (_Float16)(val - (float)h);
    }
    const int co = (j ^ (lane & 3)) * 8;   // XOR chunk swizzle
    *(half8*)(uh + co) = vh;
    *(half8*)(ul + co) = vl;
  }
  LDS_FENCE();

  const _Float16* ubase_h = u_hi + wv * 64 * 32;
  const _Float16* ubase_l = u_lo + wv * 64 * 32;
  _Float16* hb_h = h_hi + wv * 16 * 32;
  _Float16* hb_l = h_lo + wv * 16 * 32;

  float* ob = out + b * 16 * HW + row * 512 + colbase;

#pragma unroll 1
  for (int g = 0; g < 4; ++g) {
    // B-fragment of u for this 16-pixel group
    const int p = g * 16 + m;
    const int uo = p * 32 + (q ^ (m & 3)) * 8;
    const half8 b_h = *(const half8*)(ubase_h + uo);
    const half8 b_l = *(const half8*)(ubase_l + uo);

    const f32x4 z = {0.f, 0.f, 0.f, 0.f};
    f32x4 acc_a, acc_h0, acc_h1;
    acc_a  = __builtin_amdgcn_mfma_f32_16x16x32_f16(aAg_l, b_h, z, 0, 0, 0);
    acc_a  = __builtin_amdgcn_mfma_f32_16x16x32_f16(aAg_h, b_l, acc_a, 0, 0, 0);
    acc_a  = __builtin_amdgcn_mfma_f32_16x16x32_f16(aAg_h, b_h, acc_a, 0, 0, 0);
    acc_h0 = __builtin_amdgcn_mfma_f32_16x16x32_f16(aH0_l, b_h, z, 0, 0, 0);
    acc_h0 = __builtin_amdgcn_mfma_f32_16x16x32_f16(aH0_h, b_l, acc_h0, 0, 0, 0);
    acc_h0 = __builtin_amdgcn_mfma_f32_16x16x32_f16(aH0_h, b_h, acc_h0, 0, 0, 0);
    acc_h1 = __builtin_amdgcn_mfma_f32_16x16x32_f16(aH1_l, b_h, z, 0, 0, 0);
    acc_h1 = __builtin_amdgcn_mfma_f32_16x16x32_f16(aH1_h, b_l, acc_h1, 0, 0, 0);
    acc_h1 = __builtin_amdgcn_mfma_f32_16x16x32_f16(aH1_h, b_h, acc_h1, 0, 0, 0);

    // hidden: bias + relu, split fp16 hi/lo, stage through wave-private LDS
    _Float16 hh[8], hl[8];
#pragma unroll
    for (int rg = 0; rg < 4; ++rg) {
      const float v0 = fmaxf(acc_h0[rg] + bias1[rg], 0.f);
      const float v1 = fmaxf(acc_h1[rg] + bias2[rg], 0.f);
      const _Float16 a0 = (_Float16)v0;
      const _Float16 a1 = (_Float16)v1;
      hh[rg]     = a0; hl[rg]     = (_Float16)(v0 - (float)a0);
      hh[4 + rg] = a1; hl[4 + rg] = (_Float16)(v1 - (float)a1);
    }
    // write pairs at k = {4q, 4q+2, 16+4q, 16+4q+2} (swizzled chunk)
#pragma unroll
    for (int pr = 0; pr < 4; ++pr) {
      const int k = ((pr >> 1) ? 16 : 0) + 4 * q + (pr & 1) * 2;
      const int idx = m * 32 + (((k >> 3) ^ (m & 3)) << 3) + (k & 7);
      const int s = (pr >> 1) * 4 + (pr & 1) * 2;  // source index into hh/hl
      *(half2*)(hb_h + idx) = (half2){hh[s], hh[s + 1]};
      *(half2*)(hb_l + idx) = (half2){hl[s], hl[s + 1]};
    }
    LDS_FENCE();

    // gate GEMM: B-fragment of hidden
    const int ho = m * 32 + (q ^ (m & 3)) * 8;
    const half8 g_h = *(const half8*)(hb_h + ho);
    const half8 g_l = *(const half8*)(hb_l + ho);
    f32x4 acc_g;
    acc_g = __builtin_amdgcn_mfma_f32_16x16x32_f16(aG2_l, g_h, z, 0, 0, 0);
    acc_g = __builtin_amdgcn_mfma_f32_16x16x32_f16(aG2_h, g_l, acc_g, 0, 0, 0);
    acc_g = __builtin_amdgcn_mfma_f32_16x16x32_f16(aG2_h, g_h, acc_g, 0, 0, 0);

    // epilogue: out = (agg+mb) * sigmoid(gate_pre + g2b)
#pragma unroll
    for (int rg = 0; rg < 4; ++rg) {
      const float ag = acc_a[rg] + bias0[rg];
      const float gp = acc_g[rg] + bias3[rg];
      const float gt = __builtin_amdgcn_rcpf(1.f + __expf(-gp));
      ob[(4 * q + rg) * HW + g * 16 + m] = ag * gt;
    }
    LDS_FENCE();   // WAR guard before next group's h writes
  }
}

extern "C" void kernel_launch(void* const* d_in, const int* in_sizes, int n_in,
                              void* d_out, int out_size, void* d_ws, size_t ws_size,
                              hipStream_t stream) {
  // setup_inputs() order:
  // 0:x 1:qw 2:qb 3:kw 4:kb 5:mw 6:mb 7:scaling 8:g1w 9:g1b 10:g2w 11:g2b
  const float* x   = (const float*)d_in[0];
  const float* mw  = (const float*)d_in[5];
  const float* mb  = (const float*)d_in[6];
  const float* g1w = (const float*)d_in[8];
  const float* g1b = (const float*)d_in[9];
  const float* g2w = (const float*)d_in[10];
  const float* g2b = (const float*)d_in[11];
  float* out = (float*)d_out;

  _Float16* wf = (_Float16*)d_ws;                  // 8 KB fragment table
  float*    wb = (float*)((char*)d_ws + 8192);     // 4 KB bias table

  ga_prep<<<1, 64, 0, stream>>>(mw, mb, g1w, g1b, g2w, g2b, wf, wb);
  // 4096 wgs x 256 thr; wave = 64 px of one image row.
  ga_main<<<4096, 256, 0, stream>>>(x, wf, wb, out);
}